// Round 3
// baseline (358.944 us; speedup 1.0000x reference)
//
#include <hip/hip_runtime.h>
#include <math.h>

#define C 8192
#define D 1024
#define BATCH 1024
#define PM 0.95f
#define PMC 0.05f
#define INVT 10.0f

typedef __attribute__((ext_vector_type(8))) __bf16 bf16x8;
typedef __attribute__((ext_vector_type(16))) float f32x16;

#define GLOBAL_AS(p) ((const __attribute__((address_space(1))) void*)(p))
#define LDS_AS(p) ((__attribute__((address_space(3))) void*)(p))

// ---------------------------------------------------------------------------
__global__ __launch_bounds__(256) void zero_kernel(float* __restrict__ rowsum,
                                                   float* __restrict__ out) {
    int i = blockIdx.x * 256 + threadIdx.x;
    if (i < C) rowsum[i] = 0.0f;
    if (i == 0) out[0] = 0.0f;
}

// ---------------------------------------------------------------------------
// EMA + split fused. One block per class; applies the (usually empty) EMA
// chain for its class, then writes bf16 hi/lo directly in 32x32-tile MFMA
// fragment order. protos is never written back (nothing downstream reads it).
// Layout: element (row c, k) -> Phi[(rt*32+kc)*1024 + khalf*512 + (half*32+r)*8 + j]
// with rt=c>>5, r=c&31, kc=k>>5, khalf=(k>>4)&1, half=(k>>3)&1, j=k&7.
__global__ __launch_bounds__(256) void ema_split_kernel(const float* __restrict__ feat,
                                                        const int* __restrict__ labels,
                                                        const float* __restrict__ protos,
                                                        ushort* __restrict__ Phi,
                                                        ushort* __restrict__ Plo) {
    __shared__ int sl[BATCH];
    __shared__ int matches[BATCH];
    __shared__ int nmatch_s;
    __shared__ float red[4];
    const int t = threadIdx.x;
    const int c = blockIdx.x;
    if (t == 0) nmatch_s = 0;
    for (int i = t; i < BATCH; i += 256) sl[i] = labels[i];
    __syncthreads();
    for (int i = t; i < BATCH; i += 256) {
        if (sl[i] == c) { int p = atomicAdd(&nmatch_s, 1); matches[p] = i; }
    }
    __syncthreads();
    const int n = nmatch_s;

    const int w = t >> 6, lane = t & 63;
    float4 v = *(const float4*)(protos + (size_t)c * D + t * 4);

    if (n > 0) {
        if (t == 0) {                     // tiny insertion sort -> sample order
            for (int a = 1; a < n; ++a) {
                int key = matches[a]; int b = a - 1;
                while (b >= 0 && matches[b] > key) { matches[b + 1] = matches[b]; --b; }
                matches[b + 1] = key;
            }
        }
        __syncthreads();
        for (int m = 0; m < n; ++m) {
            const int idx = matches[m];
            const float4 f = *(const float4*)(feat + (size_t)idx * D + t * 4);
            v.x = v.x * PM + f.x * PMC;
            v.y = v.y * PM + f.y * PMC;
            v.z = v.z * PM + f.z * PMC;
            v.w = v.w * PM + f.w * PMC;
            float ss = v.x * v.x + v.y * v.y + v.z * v.z + v.w * v.w;
            #pragma unroll
            for (int off = 32; off > 0; off >>= 1) ss += __shfl_down(ss, off);
            if (lane == 0) red[w] = ss;
            __syncthreads();
            const float tot = red[0] + red[1] + red[2] + red[3];
            const float inv = 1.0f / fmaxf(sqrtf(tot), 1e-12f);
            v.x *= inv; v.y *= inv; v.z *= inv; v.w *= inv;
            __syncthreads();
        }
    }

    // split + write in fragment order (4 consecutive k share one 8-byte slot)
    const int k0 = t * 4;
    const int rt = c >> 5, r = c & 31;
    const int kc = k0 >> 5, khalf = (k0 >> 4) & 1, half = (k0 >> 3) & 1, j0 = k0 & 7;
    const size_t off = ((size_t)(rt * 32 + kc) * 1024) + khalf * 512 + (half * 32 + r) * 8 + j0;
    const float f[4] = {v.x, v.y, v.z, v.w};
    alignas(8) __bf16 hi4[4];
    alignas(8) __bf16 lo4[4];
    #pragma unroll
    for (int i = 0; i < 4; ++i) {
        const __bf16 hb = (__bf16)f[i];
        hi4[i] = hb;
        lo4[i] = (__bf16)(f[i] - (float)hb);
    }
    *(uint2*)(Phi + off) = *(const uint2*)hi4;
    *(uint2*)(Plo + off) = *(const uint2*)lo4;
}

// ---------------------------------------------------------------------------
// Split-bf16 Gram with 32x32x16 MFMA. Block tile 256(i) x 128(j), 4 waves in
// a 2x2 grid, each wave owns 128x64 (4x2 tiles of 32x32, 128 AGPR acc).
// Upper-triangle cover: blocks (bi,bj) with bj >= 2*bi (1056 blocks); cells
// with gi >= gj are zeroed (mirror produced via col-scatter), so rowsum ends
// as sum_neg exactly. Per BK=32: 48 glds units (1 KB each) staged by 4 waves
// (12 each), then per wave 24 ds_read_b128 + 48 MFMA (hi*hi+hi*lo+lo*hi).
__global__ __launch_bounds__(256, 2) void gram32_kernel(const ushort* __restrict__ Phi,
                                                        const ushort* __restrict__ Plo,
                                                        float* __restrict__ rowsum) {
    __shared__ alignas(16) ushort lds[48 * 512];   // 48 KB
    __shared__ float rpart[256];
    __shared__ float cpart[128];
    const int t = threadIdx.x, w = t >> 6, lane = t & 63;

    int rem = blockIdx.x, bi = 0;
    while (rem >= 64 - 2 * bi) { rem -= 64 - 2 * bi; ++bi; }
    const int bj = 2 * bi + rem;
    const int i0 = bi * 256, j0 = bj * 128;
    const bool straddle = (j0 < i0 + 256);    // block contains gi >= gj cells

    rpart[t] = 0.0f;
    if (t < 128) cpart[t] = 0.0f;

    // 12 staging units per wave; unit u = 4*r + w covers LDS [u*1KB, +1KB)
    //   u in [0,16): A-hi   [16,32): A-lo   [32,40): B-hi   [40,48): B-lo
    const ushort* gsrc[12];
    #pragma unroll
    for (int r = 0; r < 12; ++r) {
        const int u = 4 * r + w;
        const ushort* base;
        int RT;
        if (r < 4)       { base = Phi; RT = bi * 8 + (u >> 1); }
        else if (r < 8)  { base = Plo; RT = bi * 8 + ((u - 16) >> 1); }
        else if (r < 10) { base = Phi; RT = bj * 4 + ((u - 32) >> 1); }
        else             { base = Plo; RT = bj * 4 + ((u - 40) >> 1); }
        gsrc[r] = base + (size_t)RT * 32768 + (u & 1) * 512 + lane * 8;
    }

    const int qi = w >> 1, qj = w & 1;
    f32x16 acc[4][2];
    #pragma unroll
    for (int a = 0; a < 4; ++a)
        #pragma unroll
        for (int b = 0; b < 2; ++b)
            #pragma unroll
            for (int e = 0; e < 16; ++e) acc[a][b][e] = 0.0f;

    for (int kc = 0; kc < 32; ++kc) {
        #pragma unroll
        for (int r = 0; r < 12; ++r)
            __builtin_amdgcn_global_load_lds(GLOBAL_AS(gsrc[r] + kc * 1024),
                                             LDS_AS(&lds[(4 * r + w) * 512]), 16, 0, 0);
        __syncthreads();   // vmcnt(0) drain -> all 48 KB resident

        #pragma unroll
        for (int khalf = 0; khalf < 2; ++khalf) {
            bf16x8 ah[4], al[4], bh[2], bl[2];
            #pragma unroll
            for (int ti = 0; ti < 4; ++ti) {
                const int idx = ((qi * 4 + ti) * 2 + khalf) * 512 + lane * 8;
                ah[ti] = *(const bf16x8*)&lds[idx];
                al[ti] = *(const bf16x8*)&lds[8192 + idx];
            }
            #pragma unroll
            for (int tj = 0; tj < 2; ++tj) {
                const int idx = ((qj * 2 + tj) * 2 + khalf) * 512 + lane * 8;
                bh[tj] = *(const bf16x8*)&lds[16384 + idx];
                bl[tj] = *(const bf16x8*)&lds[20480 + idx];
            }
            #pragma unroll
            for (int ti = 0; ti < 4; ++ti)
                #pragma unroll
                for (int tj = 0; tj < 2; ++tj) {
                    acc[ti][tj] = __builtin_amdgcn_mfma_f32_32x32x16_bf16(ah[ti], bh[tj], acc[ti][tj], 0, 0, 0);
                    acc[ti][tj] = __builtin_amdgcn_mfma_f32_32x32x16_bf16(ah[ti], bl[tj], acc[ti][tj], 0, 0, 0);
                    acc[ti][tj] = __builtin_amdgcn_mfma_f32_32x32x16_bf16(al[ti], bh[tj], acc[ti][tj], 0, 0, 0);
                }
        }
        __syncthreads();   // frag reads done before next chunk overwrites
    }

    // epilogue: exp, triangle mask, row/col partial sums
    // C layout (32x32): col = lane&31, row = (reg&3) + 8*(reg>>2) + 4*(lane>>5)
    const int half = lane >> 5, col = lane & 31;
    float csum[2] = {0.0f, 0.0f};
    #pragma unroll
    for (int ti = 0; ti < 4; ++ti) {
        float rs[16];
        #pragma unroll
        for (int reg = 0; reg < 16; ++reg) rs[reg] = 0.0f;
        #pragma unroll
        for (int tj = 0; tj < 2; ++tj) {
            const int gj = j0 + qj * 64 + tj * 32 + col;
            #pragma unroll
            for (int reg = 0; reg < 16; ++reg) {
                const int gi = i0 + qi * 128 + ti * 32 + (reg & 3) + 8 * (reg >> 2) + 4 * half;
                float e = __expf(acc[ti][tj][reg] * INVT);
                if (straddle && gi >= gj) e = 0.0f;   // non-straddle: gi<gj always
                rs[reg] += e;
                csum[tj] += e;
            }
        }
        #pragma unroll
        for (int reg = 0; reg < 16; ++reg) {
            float v = rs[reg];
            v += __shfl_xor(v, 1); v += __shfl_xor(v, 2); v += __shfl_xor(v, 4);
            v += __shfl_xor(v, 8); v += __shfl_xor(v, 16);
            if (col == 0)
                atomicAdd(&rpart[qi * 128 + ti * 32 + (reg & 3) + 8 * (reg >> 2) + 4 * half], v);
        }
    }
    #pragma unroll
    for (int tj = 0; tj < 2; ++tj) {
        float v = csum[tj];
        v += __shfl_xor(v, 32);
        if (half == 0) atomicAdd(&cpart[qj * 64 + tj * 32 + col], v);
    }
    __syncthreads();
    atomicAdd(&rowsum[i0 + t], rpart[t]);
    if (t < 128) atomicAdd(&rowsum[j0 + t], cpart[t]);
}

// ---------------------------------------------------------------------------
// rowsum == sum_neg already (diag + lower triangle excluded in gram)
__global__ __launch_bounds__(256) void final2_kernel(const float* __restrict__ rowsum,
                                                     float* __restrict__ out) {
    __shared__ float red[4];
    const int t = threadIdx.x;
    const int i = blockIdx.x * 256 + t;
    float v = logf(rowsum[i] * (1.0f / (float)(C - 1)));
    #pragma unroll
    for (int off = 32; off > 0; off >>= 1) v += __shfl_down(v, off);
    if ((t & 63) == 0) red[t >> 6] = v;
    __syncthreads();
    if (t == 0)
        atomicAdd(out, (red[0] + red[1] + red[2] + red[3]) * (1.0f / (float)C));
}

// ---------------------------------------------------------------------------
extern "C" void kernel_launch(void* const* d_in, const int* in_sizes, int n_in,
                              void* d_out, int out_size, void* d_ws, size_t ws_size,
                              hipStream_t stream) {
    const float* feat = (const float*)d_in[0];
    const int* labels = (const int*)d_in[1];
    const float* protos = (const float*)d_in[2];
    float* out = (float*)d_out;
    float* rowsum = (float*)d_ws;                       // 32 KB
    ushort* Phi = (ushort*)((char*)d_ws + 32768);       // 16 MiB
    ushort* Plo = (ushort*)((char*)d_ws + 32768 + (size_t)C * D * sizeof(ushort));

    zero_kernel<<<32, 256, 0, stream>>>(rowsum, out);
    ema_split_kernel<<<C, 256, 0, stream>>>(feat, labels, protos, Phi, Plo);
    gram32_kernel<<<1056, 256, 0, stream>>>(Phi, Plo, rowsum);
    final2_kernel<<<C / 256, 256, 0, stream>>>(rowsum, out);
}

// Round 4
// 217.805 us; speedup vs baseline: 1.6480x; 1.6480x over previous
//
#include <hip/hip_runtime.h>
#include <math.h>

#define C 8192
#define D 1024
#define BATCH 1024
#define PM 0.95f
#define PMC 0.05f
#define INVT 10.0f

typedef __attribute__((ext_vector_type(8))) _Float16 f16x8;
typedef __attribute__((ext_vector_type(16))) float f32x16;

#define GLOBAL_AS(p) ((const __attribute__((address_space(1))) void*)(p))
#define LDS_AS(p) ((__attribute__((address_space(3))) void*)(p))

// ---------------------------------------------------------------------------
// EMA + fp16 convert, 8 classes per block (1024 blocks). Also zeroes rowsum
// and out (consumed only by later kernels in stream order).
// fp16 layout for 32x32x16 MFMA fragments: element (row c, k) ->
//   Ph[(rt*64 + kc16)*512 + (half*32 + r)*8 + j]
// with rt=c>>5, r=c&31, kc16=k>>4, half=(k>>3)&1, j=k&7.
__global__ __launch_bounds__(256) void ema_split_kernel(const float* __restrict__ feat,
                                                        const int* __restrict__ labels,
                                                        const float* __restrict__ protos,
                                                        ushort* __restrict__ Ph,
                                                        float* __restrict__ rowsum,
                                                        float* __restrict__ out) {
    __shared__ int sl[BATCH];
    __shared__ int cnt[8];
    __shared__ int mlist[8][64];
    __shared__ float red[4];
    const int t = threadIdx.x;
    const int c8 = blockIdx.x * 8;

    if (blockIdx.x < 32) rowsum[blockIdx.x * 256 + t] = 0.0f;
    if (blockIdx.x == 0 && t == 0) out[0] = 0.0f;

    if (t < 8) cnt[t] = 0;
    for (int i = t; i < BATCH; i += 256) sl[i] = labels[i];
    __syncthreads();
    for (int i = t; i < BATCH; i += 256) {
        const int l = sl[i] - c8;
        if (l >= 0 && l < 8) {
            int p = atomicAdd(&cnt[l], 1);
            if (p < 64) mlist[l][p] = i;
        }
    }
    __syncthreads();
    if (t < 8) {                       // per-class insertion sort -> sample order
        const int n = min(cnt[t], 64);
        for (int a = 1; a < n; ++a) {
            int key = mlist[t][a]; int b = a - 1;
            while (b >= 0 && mlist[t][b] > key) { mlist[t][b + 1] = mlist[t][b]; --b; }
            mlist[t][b + 1] = key;
        }
    }
    __syncthreads();

    const int w = t >> 6, lane = t & 63;
    for (int cc = 0; cc < 8; ++cc) {
        const int c = c8 + cc;
        float4 v = *(const float4*)(protos + (size_t)c * D + t * 4);
        const int n = min(cnt[cc], 64);          // block-uniform
        for (int m = 0; m < n; ++m) {
            const int idx = mlist[cc][m];
            const float4 f = *(const float4*)(feat + (size_t)idx * D + t * 4);
            v.x = v.x * PM + f.x * PMC;
            v.y = v.y * PM + f.y * PMC;
            v.z = v.z * PM + f.z * PMC;
            v.w = v.w * PM + f.w * PMC;
            float ss = v.x * v.x + v.y * v.y + v.z * v.z + v.w * v.w;
            #pragma unroll
            for (int off = 32; off > 0; off >>= 1) ss += __shfl_down(ss, off);
            if (lane == 0) red[w] = ss;
            __syncthreads();
            const float tot = red[0] + red[1] + red[2] + red[3];
            const float inv = 1.0f / fmaxf(sqrtf(tot), 1e-12f);
            v.x *= inv; v.y *= inv; v.z *= inv; v.w *= inv;
            __syncthreads();
        }
        const int k0 = t * 4;
        const int rt = c >> 5, r = c & 31;
        const size_t off = ((size_t)(rt * 64 + (k0 >> 4)) * 512)
                         + (((k0 >> 3) & 1) * 32 + r) * 8 + (k0 & 7);
        const float f[4] = {v.x, v.y, v.z, v.w};
        alignas(8) _Float16 h4[4];
        #pragma unroll
        for (int i = 0; i < 4; ++i) h4[i] = (_Float16)f[i];
        *(uint2*)(Ph + off) = *(const uint2*)h4;
    }
}

// ---------------------------------------------------------------------------
// fp16 single-product Gram, 32x32x16 MFMA. Block tile 256(i) x 128(j), 4 waves
// in 2x2, wave tile 128x64 (8 tiles x 16 AGPR acc). Upper-triangle cover
// (bj >= 2*bi, 1056 blocks); straddle blocks mask gi >= gj -> rowsum==sum_neg.
// Double-buffered LDS (24 KB/buf), ONE barrier per BK=32 chunk: chunk k+1 is
// staged via global_load_lds BEFORE computing chunk k, so the implicit
// vmcnt(0) drain at the next barrier overlaps ~16 MFMAs of compute.
__global__ __launch_bounds__(256, 2) void gram16_kernel(const ushort* __restrict__ Ph,
                                                        float* __restrict__ rowsum) {
    __shared__ ushort lds[2][12288];   // 2 x 24 KB: units 0..15 = A, 16..23 = B
    __shared__ float rpart[256];
    __shared__ float cpart[128];
    const int t = threadIdx.x, w = t >> 6, lane = t & 63;

    int rem = blockIdx.x, bi = 0;
    while (rem >= 64 - 2 * bi) { rem -= 64 - 2 * bi; ++bi; }
    const int bj = 2 * bi + rem;
    const int i0 = bi * 256, j0 = bj * 128;
    const bool straddle = (j0 < i0 + 256);

    rpart[t] = 0.0f;
    if (t < 128) cpart[t] = 0.0f;

    // 6 staging units per wave; unit u = 4*r + w; kcl = u&1 selects k-half
    const ushort* gsrc[6];
    #pragma unroll
    for (int r = 0; r < 6; ++r) {
        const int u = 4 * r + w;
        const int kcl = u & 1;
        const int rt = (u < 16) ? (bi * 8 + (u >> 1)) : (bj * 4 + ((u - 16) >> 1));
        gsrc[r] = Ph + ((size_t)rt * 64 + kcl) * 512 + lane * 8;
    }

    const int qi = w >> 1, qj = w & 1;
    f32x16 acc[4][2];
    #pragma unroll
    for (int a = 0; a < 4; ++a)
        #pragma unroll
        for (int b = 0; b < 2; ++b)
            #pragma unroll
            for (int e = 0; e < 16; ++e) acc[a][b][e] = 0.0f;

    // prologue: stage chunk 0 into buffer 0
    #pragma unroll
    for (int r = 0; r < 6; ++r)
        __builtin_amdgcn_global_load_lds(GLOBAL_AS(gsrc[r]),
                                         LDS_AS(&lds[0][(4 * r + w) * 512]), 16, 0, 0);

    for (int kc = 0; kc < 32; ++kc) {
        const int cur = kc & 1;
        __syncthreads();   // own glds (chunk kc) drained; all waves done reading buf cur^1
        if (kc < 31) {
            #pragma unroll
            for (int r = 0; r < 6; ++r)
                __builtin_amdgcn_global_load_lds(GLOBAL_AS(gsrc[r] + (size_t)(kc + 1) * 1024),
                                                 LDS_AS(&lds[cur ^ 1][(4 * r + w) * 512]), 16, 0, 0);
        }
        #pragma unroll
        for (int kcl = 0; kcl < 2; ++kcl) {
            f16x8 ah[4], bh[2];
            #pragma unroll
            for (int ti = 0; ti < 4; ++ti)
                ah[ti] = *(const f16x8*)&lds[cur][((qi * 4 + ti) * 2 + kcl) * 512 + lane * 8];
            #pragma unroll
            for (int tj = 0; tj < 2; ++tj)
                bh[tj] = *(const f16x8*)&lds[cur][(16 + (qj * 2 + tj) * 2 + kcl) * 512 + lane * 8];
            #pragma unroll
            for (int ti = 0; ti < 4; ++ti)
                #pragma unroll
                for (int tj = 0; tj < 2; ++tj)
                    acc[ti][tj] = __builtin_amdgcn_mfma_f32_32x32x16_f16(ah[ti], bh[tj], acc[ti][tj], 0, 0, 0);
        }
    }

    // epilogue: exp, triangle mask, row/col partial sums
    // C layout (32x32): col = lane&31, row = (reg&3) + 8*(reg>>2) + 4*(lane>>5)
    const int half = lane >> 5, col = lane & 31;
    float csum[2] = {0.0f, 0.0f};
    #pragma unroll
    for (int ti = 0; ti < 4; ++ti) {
        float rs[16];
        #pragma unroll
        for (int reg = 0; reg < 16; ++reg) rs[reg] = 0.0f;
        #pragma unroll
        for (int tj = 0; tj < 2; ++tj) {
            const int gj = j0 + qj * 64 + tj * 32 + col;
            #pragma unroll
            for (int reg = 0; reg < 16; ++reg) {
                const int gi = i0 + qi * 128 + ti * 32 + (reg & 3) + 8 * (reg >> 2) + 4 * half;
                float e = __expf(acc[ti][tj][reg] * INVT);
                if (straddle && gi >= gj) e = 0.0f;
                rs[reg] += e;
                csum[tj] += e;
            }
        }
        #pragma unroll
        for (int reg = 0; reg < 16; ++reg) {
            float v = rs[reg];
            v += __shfl_xor(v, 1); v += __shfl_xor(v, 2); v += __shfl_xor(v, 4);
            v += __shfl_xor(v, 8); v += __shfl_xor(v, 16);
            if (col == 0)
                atomicAdd(&rpart[qi * 128 + ti * 32 + (reg & 3) + 8 * (reg >> 2) + 4 * half], v);
        }
    }
    #pragma unroll
    for (int tj = 0; tj < 2; ++tj) {
        float v = csum[tj];
        v += __shfl_xor(v, 32);
        if (half == 0) atomicAdd(&cpart[qj * 64 + tj * 32 + col], v);
    }
    __syncthreads();
    atomicAdd(&rowsum[i0 + t], rpart[t]);
    if (t < 128) atomicAdd(&rowsum[j0 + t], cpart[t]);
}

// ---------------------------------------------------------------------------
// rowsum == sum_neg (diag + lower triangle excluded in gram)
__global__ __launch_bounds__(256) void final2_kernel(const float* __restrict__ rowsum,
                                                     float* __restrict__ out) {
    __shared__ float red[4];
    const int t = threadIdx.x;
    const int i = blockIdx.x * 256 + t;
    float v = logf(rowsum[i] * (1.0f / (float)(C - 1)));
    #pragma unroll
    for (int off = 32; off > 0; off >>= 1) v += __shfl_down(v, off);
    if ((t & 63) == 0) red[t >> 6] = v;
    __syncthreads();
    if (t == 0)
        atomicAdd(out, (red[0] + red[1] + red[2] + red[3]) * (1.0f / (float)C));
}

// ---------------------------------------------------------------------------
extern "C" void kernel_launch(void* const* d_in, const int* in_sizes, int n_in,
                              void* d_out, int out_size, void* d_ws, size_t ws_size,
                              hipStream_t stream) {
    const float* feat = (const float*)d_in[0];
    const int* labels = (const int*)d_in[1];
    const float* protos = (const float*)d_in[2];
    float* out = (float*)d_out;
    float* rowsum = (float*)d_ws;                  // 32 KB
    ushort* Ph = (ushort*)((char*)d_ws + 32768);   // 16 MiB fp16 protos

    ema_split_kernel<<<C / 8, 256, 0, stream>>>(feat, labels, protos, Ph, rowsum, out);
    gram16_kernel<<<1056, 256, 0, stream>>>(Ph, rowsum);
    final2_kernel<<<C / 256, 256, 0, stream>>>(rowsum, out);
}